// Round 3
// baseline (167.657 us; speedup 1.0000x reference)
//
#include <hip/hip_runtime.h>
#include <hip/hip_bf16.h>

typedef __attribute__((ext_vector_type(4))) float f32x4;
typedef __attribute__((ext_vector_type(8))) short bf16x8;
typedef __attribute__((ext_vector_type(4))) short short4v;
typedef __attribute__((ext_vector_type(8))) short short8v;

#define BSTRIDE 40   // 32 k-shorts + 8 pad = 80 B rows; quad-bank stride 5 (odd) -> flat b128 bank histogram
#define ASTRIDE 40
#define CSTRIDE 132  // fp32 epilogue: quad offset 528 dw = 16 mod 32 -> 2-way (free)

__device__ __forceinline__ short f2bf(float f) {
  __hip_bfloat16 h = __float2bfloat16(f);
  return __builtin_bit_cast(short, h);
}

#define GLOAD_LDS16(gp, lp)                                                     \
  __builtin_amdgcn_global_load_lds(                                             \
      (const __attribute__((address_space(1))) void*)(gp),                      \
      (__attribute__((address_space(3))) void*)(lp), 16, 0, 0)

// ---------------------------------------------------------------------------
// GEMM view: C[8192 x 512] = A[8192 x 1024] * B[1024 x 512], k = j*4 + kc,
// kc -> x component {0,1,2,4}. Block tile: 32 rows x 128 cols, where cols =
// [c0 rows of points iq*64..iq*64+63 | c4 rows of the SAME points] so the
// epilogue writes full 32 B multivectors (no partial-line HBM writes).
// Bp image in d_ws: [it 0..31][iq 0..3][hc 0..1][il 0..63][BSTRIDE shorts]
//   hc=0 (c0): {W0, W1, W2, 0}   hc=1 (c4): {0, W2, -W1, W0}
// ---------------------------------------------------------------------------
__global__ __launch_bounds__(256) void ga_prep_B(const float* __restrict__ W,
                                                 short* __restrict__ Bp) {
  const int gid = blockIdx.x * 256 + threadIdx.x;  // 16384 rows
  const int il = gid & 63;
  const int hc = (gid >> 6) & 1;   // wave-uniform
  const int iq = (gid >> 7) & 3;
  const int it = gid >> 9;
  const int i = iq * 64 + il;
  const float4* W4 = (const float4*)W;

  short8v out[5];
  out[4] = short8v{0, 0, 0, 0, 0, 0, 0, 0};  // pad shorts 32..39
#pragma unroll
  for (int jp = 0; jp < 8; ++jp) {
    const float4 wv = W4[((it * 8 + jp) * 256 + i) * 2];  // comps 0..3 of W[j][i][:]
    short s0, s1, s2, s3;
    if (!hc) { s0 = f2bf(wv.x); s1 = f2bf(wv.y); s2 = f2bf(wv.z); s3 = 0; }
    else     { s0 = 0; s1 = f2bf(wv.z); s2 = f2bf(-wv.y); s3 = f2bf(wv.x); }
    out[jp >> 1][(jp & 1) * 4 + 0] = s0;
    out[jp >> 1][(jp & 1) * 4 + 1] = s1;
    out[jp >> 1][(jp & 1) * 4 + 2] = s2;
    out[jp >> 1][(jp & 1) * 4 + 3] = s3;
  }
  short8v* dst = (short8v*)&Bp[(size_t)gid * BSTRIDE];
#pragma unroll
  for (int c = 0; c < 5; ++c) dst[c] = out[c];
}

// ---------------------------------------------------------------------------
// Main: 1024 blocks x 128 threads (2 waves). LDS 25.6 KB -> 6 blocks/CU.
// Single barrier per K-step; double-buffered A (reg->LDS) and B
// (global_load_lds). x loads land 2 tiles ahead so they are never waited on
// in the iteration that issues them. XCD swizzle: the 4 iq-blocks sharing an
// x row-tile get blockIdx = g + 8*iq + 32*hi -> same XCD -> x reused via L2.
// ---------------------------------------------------------------------------
__global__ __launch_bounds__(128, 3) void ga_mv_main(
    const float* __restrict__ x, const short* __restrict__ Bp,
    const float* __restrict__ bias, float* __restrict__ y) {
  __shared__ __align__(16) short B_lds[2][128 * BSTRIDE];  // 2 x 10240 B
  __shared__ __align__(16) short A_lds[2][32 * ASTRIDE];   // 2 x 2560 B
  float* c_lds = (float*)&B_lds[0][0];  // epilogue alias: 32*132*4 = 16896 <= 20480

  const int t = threadIdx.x;
  const int id = blockIdx.x;
  const int g = id & 7;             // XCD slot
  const int iq = (id >> 3) & 3;     // 64-point column group
  const int bm = (id >> 5) * 8 + g; // 0..255: 32-row tile
  const int lane = t & 63;
  const int w = t >> 6;             // wave 0 -> c0 cols, wave 1 -> c4 cols
  const int ln = lane & 15;
  const int quad = lane >> 4;

  // A staging: slot s in {t, t+128}: row = s>>3 (0..31), aj = s&7
  const int ar = t >> 3;   // 0..15 (slot1 row = ar+16)
  const int aj = t & 7;
  const float* xrow0 = x + (size_t)(bm * 32 + ar) * 2048 + aj * 8;

  float4 xr0, xr1;
  float xs0, xs1;

#define LOAD_X(tile)                                   \
  {                                                    \
    const float* p0 = xrow0 + (tile) * 64;             \
    const float* p1 = p0 + 16 * 2048;                  \
    xr0 = *(const float4*)p0; xs0 = p0[4];             \
    xr1 = *(const float4*)p1; xs1 = p1[4];             \
  }

#define CONV_A(buf)                                                        \
  {                                                                        \
    short4v a;                                                             \
    a[0] = f2bf(xr0.x); a[1] = f2bf(xr0.y); a[2] = f2bf(xr0.z);            \
    a[3] = f2bf(xs0);                                                      \
    *(short4v*)&A_lds[buf][ar * ASTRIDE + aj * 4] = a;                     \
    a[0] = f2bf(xr1.x); a[1] = f2bf(xr1.y); a[2] = f2bf(xr1.z);            \
    a[3] = f2bf(xs1);                                                      \
    *(short4v*)&A_lds[buf][(ar + 16) * ASTRIDE + aj * 4] = a;              \
  }

#define STAGE_B(tile, buf)                                                 \
  {                                                                        \
    const char* src = (const char*)Bp + ((size_t)(tile) * 4 + iq) * 10240; \
    char* dst = (char*)&B_lds[buf][0];                                     \
    _Pragma("unroll")                                                      \
    for (int r = 0; r < 5; ++r)                                            \
      GLOAD_LDS16(src + r * 2048 + t * 16, dst + r * 2048 + t * 16);       \
  }

  // ---- prologue: tile 0 staged, tile 1 x in regs ----
  STAGE_B(0, 0);
  LOAD_X(0);
  CONV_A(0);      // waits tile-0 x loads
  LOAD_X(1);
  __syncthreads();  // drains B glds + tile-1 x loads (once)

  f32x4 acc[8] = {};

  for (int it = 0; it < 32; ++it) {
    const int cur = it & 1, nxt = cur ^ 1;
    if (it < 31) {
      CONV_A(nxt);        // xr = tile it+1, already drained by prev barrier
      STAGE_B(it + 1, nxt);
      if (it < 30) LOAD_X(it + 2);  // never waited on this iteration
    }
    const bf16x8 a0 = *(const bf16x8*)&A_lds[cur][ln * ASTRIDE + quad * 8];
    const bf16x8 a1 = *(const bf16x8*)&A_lds[cur][(16 + ln) * ASTRIDE + quad * 8];
#pragma unroll
    for (int n = 0; n < 4; ++n) {
      const bf16x8 b =
          *(const bf16x8*)&B_lds[cur][(w * 64 + n * 16 + ln) * BSTRIDE + quad * 8];
      acc[n]     = __builtin_amdgcn_mfma_f32_16x16x32_bf16(a0, b, acc[n], 0, 0, 0);
      acc[4 + n] = __builtin_amdgcn_mfma_f32_16x16x32_bf16(a1, b, acc[4 + n], 0, 0, 0);
    }
    __syncthreads();  // single barrier: drains nxt-tile B glds, guards buffers
  }

  // ---- epilogue: acc -> c_lds, then full-multivector contiguous y writes ----
  // C/D layout (16x16): col = ln, row = quad*4 + reg
#pragma unroll
  for (int n = 0; n < 4; ++n)
#pragma unroll
    for (int r = 0; r < 4; ++r) {
      c_lds[(quad * 4 + r) * CSTRIDE + w * 64 + n * 16 + ln] = acc[n][r];
      c_lds[(16 + quad * 4 + r) * CSTRIDE + w * 64 + n * 16 + ln] = acc[4 + n][r];
    }
  __syncthreads();

  const int h = t & 1;       // 0 -> mv comps 0..3 (c0), 1 -> comps 4..7 (c4)
  const int il = t >> 1;     // point within 64-col group
  const float4 bv = ((const float4*)bias)[(iq * 64 + il) * 2 + h];
  float4* y4 = (float4*)y;
#pragma unroll
  for (int r = 0; r < 32; ++r) {
    float4 o = bv;
    o.x += c_lds[r * CSTRIDE + h * 64 + il];  // +c0 into comp0 / +c4 into comp4
    y4[((size_t)(bm * 32 + r) * 256 + iq * 64 + il) * 2 + h] = o;  // 2KB runs
  }
}

extern "C" void kernel_launch(void* const* d_in, const int* in_sizes, int n_in,
                              void* d_out, int out_size, void* d_ws, size_t ws_size,
                              hipStream_t stream) {
  const float* x = (const float*)d_in[0];
  const float* W = (const float*)d_in[1];
  const float* bias = (const float*)d_in[2];
  float* y = (float*)d_out;
  short* Bp = (short*)d_ws;  // 32*4*2*64*40*2 = 1,310,720 B

  ga_prep_B<<<dim3(64), dim3(256), 0, stream>>>(W, Bp);
  ga_mv_main<<<dim3(1024), dim3(128), 0, stream>>>(x, Bp, bias, y);
}